// Round 17
// baseline (20103.922 us; speedup 1.0000x reference)
//
#include <hip/hip_runtime.h>
#include <hip/hip_bf16.h>
#include <math.h>

// Shapes: B=256, T=1024, F=128, D=256, UNITS=64. All inputs f32; out f32 [B,T,D].
//
// BIT-REPLICA of the jax-CPU (XLA) f32 pipeline (r0-r16 synthesis: the
// system is mostly-contracting with intermittent expansion bursts; flip time
// is quasi-random in the per-step noise realization [f64: 711, f32: >=799,
// f64+f32mm1: >=932] -> only a near-bit-exact replica of the reference
// pipeline rides its trajectory to the end).
//  - gemms: single sequential ascending-k fmaf chain per output element
//    (Eigen gebp / oneDNN brgemm / OpenBLAS microkernels all do this)
//  - z = fmaf(shifted, u, h1)  (XLA JIT contracts mul+add)
//  - tanh: XLA EmitFastTanh (with_fma): |x|<0.0004 -> x; clamp to
//    +-7.99881172180175781f; Horner-fmaf rational; f32 divide
//  - straight store, no damping.

__device__ __forceinline__ float xla_tanh(float x) {
    const float kClamp = 7.99881172180175781f;
    float xc = fminf(fmaxf(x, -kClamp), kClamp);
    float x2 = xc * xc;
    float num = -2.76076847742355e-16f;
    num = fmaf(x2, num, 2.00018790482477e-13f);
    num = fmaf(x2, num, -8.60467152213735e-11f);
    num = fmaf(x2, num, 5.12229709037114e-08f);
    num = fmaf(x2, num, 1.48572235717979e-05f);
    num = fmaf(x2, num, 6.37261928875436e-04f);
    num = fmaf(x2, num, 4.89352455891786e-03f);
    num = xc * num;
    float den = 1.19825839466702e-06f;
    den = fmaf(x2, den, 1.18534705686654e-04f);
    den = fmaf(x2, den, 2.26843463243900e-03f);
    den = fmaf(x2, den, 4.89352518554385e-03f);
    return (fabsf(x) < 0.0004f) ? x : (num / den);
}

__global__ __launch_bounds__(256, 1)
void lrs_xla(const float* __restrict__ x, const float* __restrict__ K,
             const float* __restrict__ R, const float* __restrict__ bias,
             float* __restrict__ out) {
    const int b = blockIdx.x;    // grid = 256, one batch row per block
    const int d = threadIdx.x;   // 0..255, one output column per thread

    __shared__ float dxs[128];   // dx_t
    __shared__ float dh_s[256];  // h_{t-1} - h_{t-2}
    __shared__ float h1_s[256];  // h_{t-1}

    float kc[128];               // K[:,d]
#pragma unroll
    for (int j = 0; j < 128; ++j) kc[j] = K[j * 256 + d];
    float rcf[256];              // R[:,d]
#pragma unroll
    for (int i = 0; i < 256; ++i) rcf[i] = R[(size_t)i * 256 + d];
    const float bd = bias[d];    // zeros in this problem

    dh_s[d] = 0.0f;
    h1_s[d] = 0.0f;
    float h1 = 0.0f;
    __syncthreads();

    const float* xr   = x   + (size_t)b * (1024 * 128);
    float*       orow = out + (size_t)b * (1024 * 256);

    for (int t = 0; t < 1024; ++t) {
        if (d < 128) {
            const float xt = xr[t * 128 + d];
            const float xp = (t > 0) ? xr[(t - 1) * 128 + d] : 0.0f;
            dxs[d] = xt - xp;                    // f32 sub (x_prev init = 0)
        }
        __syncthreads();

        // mm1 = dx @ K[:,d] : single sequential ascending-k fmaf chain
        float mm1 = 0.0f;
        for (int j = 0; j < 128; ++j) mm1 = fmaf(dxs[j], kc[j], mm1);

        // mm2 = dh @ R[:,d] : single sequential ascending-k fmaf chain
        float mm2 = 0.0f;
        for (int i = 0; i < 256; ++i) mm2 = fmaf(dh_s[i], rcf[i], mm2);

        // u = (mm1 + mm2) + bias   (left-to-right, f32)
        const float u = (mm1 + mm2) + bd;

        // shifted = [ones | h1[:, :-64]]
        const float sh = (d < 64) ? 1.0f : h1_s[d - 64];

        // ht = xla_tanh(h1 + shifted*u), mul+add contracted to fma (XLA JIT)
        const float z  = fmaf(sh, u, h1);
        const float hn = xla_tanh(z);

        orow[t * 256 + d] = hn;                  // straight store

        __syncthreads();
        dh_s[d] = hn - h1;                       // f32 sub
        h1_s[d] = hn;
        h1 = hn;
        __syncthreads();
    }
}

extern "C" void kernel_launch(void* const* d_in, const int* in_sizes, int n_in,
                              void* d_out, int out_size, void* d_ws, size_t ws_size,
                              hipStream_t stream) {
    // Size-based mapping (element counts); fallback to dict order.
    const float* x = nullptr; const float* K = nullptr;
    const float* R = nullptr; const float* bias = nullptr;
    for (int i = 0; i < n_in; ++i) {
        switch (in_sizes[i]) {
            case 33554432: x    = (const float*)d_in[i]; break;
            case 32768:    K    = (const float*)d_in[i]; break;
            case 65536:    R    = (const float*)d_in[i]; break;
            case 256:      bias = (const float*)d_in[i]; break;
            default: break;
        }
    }
    if (!x || !K || !R || !bias) {
        x    = (const float*)d_in[0];
        K    = (const float*)d_in[1];
        R    = (const float*)d_in[2];
        bias = (const float*)d_in[3];
    }
    float* out = (float*)d_out;

    lrs_xla<<<256, 256, 0, stream>>>(x, K, R, bias, out);
}